// Round 4
// baseline (436.606 us; speedup 1.0000x reference)
//
#include <hip/hip_runtime.h>

#define NCAM 6
#define CCH  128
#define IH   64
#define IW   176
#define NQ   640000           // 200*200*16
#define PIX  (IH * IW)        // 11264 = 352*32
#define QT   32               // queries per tile
#define NT   8                // tiles per block (grid-stride persistence)
#define NBLK (NQ / (QT * NT)) // 2500 blocks
#define LSTRIDE 129           // odd LDS stride: phase-C reads 2-way max (free)

typedef float f32x2 __attribute__((ext_vector_type(2)));
typedef float f32x4 __attribute__((ext_vector_type(4)));

// ---------------------------------------------------------------------------
// Kernel 1: transpose img_feats (cam, c, y, x) -> (cam, y, x, c). ~15 us.
// Source reads single-use -> non-temporal; keep L2/L3 for imgT (reused by
// the gather kernel).
// ---------------------------------------------------------------------------
__global__ __launch_bounds__(256) void transpose_kernel(
    const float* __restrict__ in, float* __restrict__ out) {
    __shared__ float tile[32][33];
    const int cam   = blockIdx.z;
    const int pbase = blockIdx.x * 32;
    const int cbase = blockIdx.y * 32;
    const int tx = threadIdx.x, ty = threadIdx.y;

    const float* src = in  + (size_t)cam * CCH * PIX;
    float*       dst = out + (size_t)cam * PIX * CCH;

    #pragma unroll
    for (int j = 0; j < 4; ++j) {
        int c = cbase + ty + j * 8;
        tile[ty + j * 8][tx] =
            __builtin_nontemporal_load(&src[(size_t)c * PIX + (pbase + tx)]);
    }
    __syncthreads();
    #pragma unroll
    for (int j = 0; j < 4; ++j) {
        int p = pbase + ty + j * 8;
        dst[(size_t)p * CCH + (cbase + tx)] = tile[tx][ty + j * 8];
    }
}

// ---------------------------------------------------------------------------
// Kernel 2 (R3): pipelined LDS-staged gather. Each block owns NT=8
// consecutive tiles of QT=32 queries, double-buffered in LDS.
// R1/R2 lesson: occupancy 16->32 waves/CU was NEUTRAL -> not wave-count
// bound. New theory: A->B->C phase lockstep left the scattered-read issue
// duty cycle ~30%. Pipeline (T14 issue-early/write-late): loads for tile
// t+1 are in flight WHILE phase C of tile t does LDS reads + NT stores.
// Steady state overlaps ~400-900cy L3 read latency with the store phase.
//  resolve(t+1) -> barrier -> ISSUE loads(t+1) -> C(t) -> COMMIT(t+1) -> flip
// LDS: 2*(32*129*4 + 32*8) = 33.5 KB -> 4 blocks/CU, 16 waves/CU (same as
// the measured-419us R0 kernel: delta attributable to pipelining only).
// ---------------------------------------------------------------------------
__global__ __launch_bounds__(256, 4) void gather_pipe_kernel(
    const float* __restrict__ imgT,     // (cam, y, x, c)
    const float* __restrict__ points,   // (cam, NQ, 2)
    const int*   __restrict__ valid,    // (cam, NQ) int32
    float*       __restrict__ out) {    // (c, NQ)
    __shared__ float feat[2][QT * LSTRIDE];
    __shared__ int   sbase[2][QT];
    __shared__ float sscale[2][QT];

    const int t     = threadIdx.x;
    const int grp   = t >> 5;      // 0..7
    const int lane  = t & 31;
    const int tile0 = blockIdx.x * NT;

    // ---- Phase A resolve for tile `tile`, into slot `slot` (threads 0..31)
    auto resolve = [&](int tile, int slot) {
        const int q = tile * QT + t;
        int sel = -1;
        #pragma unroll
        for (int cam = 0; cam < NCAM; ++cam)
            if (__builtin_nontemporal_load(&valid[(size_t)cam * NQ + q]) != 0)
                sel = cam;                                  // highest valid
        const int cam = (sel >= 0) ? sel : 0;
        sscale[slot][t] = (sel >= 0) ? 1.0f : 0.0f;
        const f32x2 pt = __builtin_nontemporal_load(
            (const f32x2*)points + (size_t)cam * NQ + q);
        const int x = __float2int_rn(pt.x);   // RNE == jnp.round
        const int y = __float2int_rn(pt.y);
        sbase[slot][t] = ((cam * IH + y) * IW + x) * CCH;   // word offset
    };

    f32x4 r[4];   // in-flight 512B vectors (4 queries per thread-group role)

    // ---- ISSUE: start coalesced 512B reads for slot's tile into regs ----
    auto issue = [&](int slot) {
        #pragma unroll
        for (int i = 0; i < 4; ++i) {
            const int ql = i * 8 + grp;
            r[i] = *((const f32x4*)(imgT + sbase[slot][ql]) + lane);
        }
    };
    // ---- COMMIT: regs -> LDS (scaled). Compiler places the vmcnt wait here.
    auto commit = [&](int slot) {
        #pragma unroll
        for (int i = 0; i < 4; ++i) {
            const int ql = i * 8 + grp;
            const float s = sscale[slot][ql];
            const int w = ql * LSTRIDE + 4 * lane;
            feat[slot][w + 0] = r[i].x * s;
            feat[slot][w + 1] = r[i].y * s;
            feat[slot][w + 2] = r[i].z * s;
            feat[slot][w + 3] = r[i].w * s;
        }
    };

    // ---- Prologue: fill buffer 0 for tile 0 ----
    if (t < QT) resolve(tile0, 0);
    __syncthreads();
    issue(0);
    commit(0);

    int cur = 0;
    for (int tt = 0; tt < NT; ++tt) {
        const int nxt = cur ^ 1;
        if (tt + 1 < NT && t < QT) resolve(tile0 + tt + 1, nxt);
        __syncthreads();   // feat[cur] committed + sbase[nxt] visible
        if (tt + 1 < NT) issue(nxt);   // loads in flight during phase C

        // ---- Phase C: LDS -> out, non-temporal float4 stores ----
        {
            const int qbase = (tile0 + tt) * QT;
            const int l    = t & 63;
            const int wv   = t >> 6;      // wave id 0..3
            const int qq   = l & 7;       // q-quad 0..7
            const int csub = l >> 3;      // 0..7
            #pragma unroll
            for (int iter = 0; iter < 4; ++iter) {
                const int c    = iter * 32 + wv * 8 + csub;
                const int qoff = 4 * qq;
                f32x4 v;
                v.x = feat[cur][(qoff + 0) * LSTRIDE + c];
                v.y = feat[cur][(qoff + 1) * LSTRIDE + c];
                v.z = feat[cur][(qoff + 2) * LSTRIDE + c];
                v.w = feat[cur][(qoff + 3) * LSTRIDE + c];
                __builtin_nontemporal_store(
                    v, (f32x4*)(out + (size_t)c * NQ + qbase + qoff));
            }
        }

        if (tt + 1 < NT) commit(nxt);  // waits vmcnt, writes LDS
        cur = nxt;
        // barrier at top of next iteration covers feat[nxt]/sbase hazards
    }
}

// ---------------------------------------------------------------------------
// Fallback: direct gather from (cam, c, y, x) if workspace too small.
// ---------------------------------------------------------------------------
__global__ __launch_bounds__(256) void gather_direct_kernel(
    const float* __restrict__ img,
    const float* __restrict__ points,
    const int*   __restrict__ valid,
    float*       __restrict__ out) {
    const int q = blockIdx.x * 256 + threadIdx.x;

    int sel = -1;
    #pragma unroll
    for (int cam = 0; cam < NCAM; ++cam)
        if (valid[(size_t)cam * NQ + q] != 0) sel = cam;

    const float scale = (sel >= 0) ? 1.0f : 0.0f;
    const int cam = (sel >= 0) ? sel : 0;

    const float2 pt = ((const float2*)points)[(size_t)cam * NQ + q];
    const int x = __float2int_rn(pt.x);
    const int y = __float2int_rn(pt.y);

    const float* src = img + ((size_t)cam * CCH * IH + y) * IW + x;
    #pragma unroll 8
    for (int c = 0; c < CCH; ++c)
        out[(size_t)c * NQ + q] = src[(size_t)c * PIX] * scale;
}

extern "C" void kernel_launch(void* const* d_in, const int* in_sizes, int n_in,
                              void* d_out, int out_size, void* d_ws, size_t ws_size,
                              hipStream_t stream) {
    const float* img    = (const float*)d_in[0];
    const float* points = (const float*)d_in[1];
    const int*   valid  = (const int*)  d_in[2];
    float*       out    = (float*)d_out;

    const size_t need = (size_t)NCAM * CCH * IH * IW * sizeof(float);
    if (ws_size >= need) {
        float* imgT = (float*)d_ws;
        dim3 tb(32, 8, 1);
        dim3 tg(PIX / 32, CCH / 32, NCAM);
        transpose_kernel<<<tg, tb, 0, stream>>>(img, imgT);
        gather_pipe_kernel<<<NBLK, 256, 0, stream>>>(imgT, points, valid, out);
    } else {
        gather_direct_kernel<<<NQ / 256, 256, 0, stream>>>(img, points, valid, out);
    }
}

// Round 6
// 407.912 us; speedup vs baseline: 1.0703x; 1.0703x over previous
//
#include <hip/hip_runtime.h>

#define NCAM 6
#define CCH  128
#define IH   64
#define IW   176
#define NQ   640000           // 200*200*16
#define PIX  (IH * IW)        // 11264
#define QT   128              // queries per block (R5: write 512B/row/block)
#define CHALF 64              // channels per half-pass (LDS fits 128q x 64c)
#define FSTR  67              // feat stride: 64 c + 3 pad -> 2-way banks (free)

typedef float f32x2 __attribute__((ext_vector_type(2)));
typedef float f32x4 __attribute__((ext_vector_type(4)));

// ---------------------------------------------------------------------------
// Kernel 1: transpose img_feats (cam, c, y, x) -> (cam, y, x, c). ~15 us.
// ---------------------------------------------------------------------------
__global__ __launch_bounds__(256) void transpose_kernel(
    const float* __restrict__ in, float* __restrict__ out) {
    __shared__ float tile[32][33];
    const int cam   = blockIdx.z;
    const int pbase = blockIdx.x * 32;
    const int cbase = blockIdx.y * 32;
    const int tx = threadIdx.x, ty = threadIdx.y;

    const float* src = in  + (size_t)cam * CCH * PIX;
    float*       dst = out + (size_t)cam * PIX * CCH;

    #pragma unroll
    for (int j = 0; j < 4; ++j) {
        int c = cbase + ty + j * 8;
        tile[ty + j * 8][tx] =
            __builtin_nontemporal_load(&src[(size_t)c * PIX + (pbase + tx)]);
    }
    __syncthreads();
    #pragma unroll
    for (int j = 0; j < 4; ++j) {
        int p = pbase + ty + j * 8;
        dst[(size_t)p * CCH + (cbase + tx)] = tile[tx][ty + j * 8];
    }
}

// ---------------------------------------------------------------------------
// Kernel 2 (R5): wide-tile gather. QT=128 queries/block, 512 threads.
// R0-R4 lessons: NT hints -3%, occupancy null, pipelining -5% -> the gather
// is throughput-bound, not latency/residency-bound. Remaining theories:
//  (A) scattered 512B L3-read path ceiling; (B) HBM write row-thrash from
//  128B-per-row-per-block write granularity (2.56M row visits/iter ~ at the
//  ~11G/s activate ceiling). This kernel tests (B): each (c, block) now
//  writes a contiguous 512B span (4x larger), read structure preserved.
// Structure per block (two c-half passes, h = 0,1):
//  A) threads 0..127 resolve cam/scale/base (NT loads).
//  B) 32 groups x 16 lanes: per query read 256B (this c-half) as 16-lane
//     f32x4 -> LDS feat[q][67]; banks (3*grp + 4*lane) mod 32 = 2-way, free.
//  C) 8 waves x (csub 0..3): c = h*64 + iter*32 + wv*4 + csub; per c store
//     two 256B NT f32x4 spans (qh = 0,1) -> 512B contiguous per (c,block).
//     Bank: (12*qq + csub) mod 32 -> exactly 2 lanes/bank, free.
// LDS: 128*67*4 + 128*8 = 35.4 KB -> 4 blocks/CU = 32 waves/CU (full).
// ---------------------------------------------------------------------------
__global__ __launch_bounds__(512, 8) void gather_wide_kernel(
    const float* __restrict__ imgT,     // (cam, y, x, c)
    const float* __restrict__ points,   // (cam, NQ, 2)
    const int*   __restrict__ valid,    // (cam, NQ) int32
    float*       __restrict__ out) {    // (c, NQ)
    __shared__ float feat[QT * FSTR];   // [q][67], c-half major
    __shared__ int   sbase[QT];
    __shared__ float sscale[QT];

    const int t     = threadIdx.x;
    const int qbase = blockIdx.x * QT;

    // ---- Phase A: resolve ----
    if (t < QT) {
        const int q = qbase + t;
        int sel = -1;
        #pragma unroll
        for (int cam = 0; cam < NCAM; ++cam)
            if (__builtin_nontemporal_load(&valid[(size_t)cam * NQ + q]) != 0)
                sel = cam;                                  // highest valid
        const int cam = (sel >= 0) ? sel : 0;
        sscale[t] = (sel >= 0) ? 1.0f : 0.0f;
        const f32x2 pt = __builtin_nontemporal_load(
            (const f32x2*)points + (size_t)cam * NQ + q);
        const int x = __float2int_rn(pt.x);   // RNE == jnp.round
        const int y = __float2int_rn(pt.y);
        sbase[t] = ((cam * IH + y) * IW + x) * CCH;   // word offset, < 2^31
    }
    __syncthreads();

    const int grp16  = t >> 4;     // 0..31
    const int lane16 = t & 15;
    const int l      = t & 63;
    const int wv     = t >> 6;     // wave 0..7
    const int qq     = l & 15;     // 0..15
    const int csub   = l >> 4;     // 0..3

    #pragma unroll
    for (int h = 0; h < 2; ++h) {
        // ---- Phase B: 256B coalesced reads (c-half h) -> LDS ----
        #pragma unroll
        for (int i = 0; i < 4; ++i) {
            const int ql = i * 32 + grp16;
            const float s = sscale[ql];
            const f32x4 v =
                *((const f32x4*)(imgT + sbase[ql] + h * CHALF) + lane16);
            const int w = ql * FSTR + 4 * lane16;
            feat[w + 0] = v.x * s;
            feat[w + 1] = v.y * s;
            feat[w + 2] = v.z * s;
            feat[w + 3] = v.w * s;
        }
        __syncthreads();

        // ---- Phase C: LDS -> out, NT f32x4; 512B contiguous per (c,block) ----
        #pragma unroll
        for (int qh = 0; qh < 2; ++qh) {
            #pragma unroll
            for (int iter = 0; iter < 2; ++iter) {
                const int cl   = iter * 32 + wv * 4 + csub;   // 0..63
                const int c    = h * CHALF + cl;
                const int qoff = qh * 64 + 4 * qq;            // 0..124
                f32x4 v;
                v.x = feat[(qoff + 0) * FSTR + cl];
                v.y = feat[(qoff + 1) * FSTR + cl];
                v.z = feat[(qoff + 2) * FSTR + cl];
                v.w = feat[(qoff + 3) * FSTR + cl];
                __builtin_nontemporal_store(
                    v, (f32x4*)(out + (size_t)c * NQ + qbase + qoff));
            }
        }
        __syncthreads();   // next half overwrites feat
    }
}

// ---------------------------------------------------------------------------
// Fallback: direct gather from (cam, c, y, x) if workspace too small.
// ---------------------------------------------------------------------------
__global__ __launch_bounds__(256) void gather_direct_kernel(
    const float* __restrict__ img,
    const float* __restrict__ points,
    const int*   __restrict__ valid,
    float*       __restrict__ out) {
    const int q = blockIdx.x * 256 + threadIdx.x;

    int sel = -1;
    #pragma unroll
    for (int cam = 0; cam < NCAM; ++cam)
        if (valid[(size_t)cam * NQ + q] != 0) sel = cam;

    const float scale = (sel >= 0) ? 1.0f : 0.0f;
    const int cam = (sel >= 0) ? sel : 0;

    const float2 pt = ((const float2*)points)[(size_t)cam * NQ + q];
    const int x = __float2int_rn(pt.x);
    const int y = __float2int_rn(pt.y);

    const float* src = img + ((size_t)cam * CCH * IH + y) * IW + x;
    #pragma unroll 8
    for (int c = 0; c < CCH; ++c)
        out[(size_t)c * NQ + q] = src[(size_t)c * PIX] * scale;
}

extern "C" void kernel_launch(void* const* d_in, const int* in_sizes, int n_in,
                              void* d_out, int out_size, void* d_ws, size_t ws_size,
                              hipStream_t stream) {
    const float* img    = (const float*)d_in[0];
    const float* points = (const float*)d_in[1];
    const int*   valid  = (const int*)  d_in[2];
    float*       out    = (float*)d_out;

    const size_t need = (size_t)NCAM * CCH * IH * IW * sizeof(float);
    if (ws_size >= need) {
        float* imgT = (float*)d_ws;
        dim3 tb(32, 8, 1);
        dim3 tg(PIX / 32, CCH / 32, NCAM);
        transpose_kernel<<<tg, tb, 0, stream>>>(img, imgT);
        gather_wide_kernel<<<NQ / QT, 512, 0, stream>>>(imgT, points, valid, out);
    } else {
        gather_direct_kernel<<<NQ / 256, 256, 0, stream>>>(img, points, valid, out);
    }
}

// Round 9
// 403.367 us; speedup vs baseline: 1.0824x; 1.0113x over previous
//
#include <hip/hip_runtime.h>

#define NCAM 6
#define CCH  128
#define IH   64
#define IW   176
#define NQ   640000           // 200*200*16
#define PIX  (IH * IW)        // 11264
#define QT   128              // queries per block
#define CHALF 64              // channels per half-pass (LDS fits 128q x 64c)
#define FSTR  67              // feat stride: 64 c + 3 pad -> 2-way banks (free)

typedef float f32x2 __attribute__((ext_vector_type(2)));
typedef float f32x4 __attribute__((ext_vector_type(4)));

// ---------------------------------------------------------------------------
// Kernel 1: transpose img_feats (cam, c, y, x) -> (cam, y, x, c). ~15 us.
// ---------------------------------------------------------------------------
__global__ __launch_bounds__(256) void transpose_kernel(
    const float* __restrict__ in, float* __restrict__ out) {
    __shared__ float tile[32][33];
    const int cam   = blockIdx.z;
    const int pbase = blockIdx.x * 32;
    const int cbase = blockIdx.y * 32;
    const int tx = threadIdx.x, ty = threadIdx.y;

    const float* src = in  + (size_t)cam * CCH * PIX;
    float*       dst = out + (size_t)cam * PIX * CCH;

    #pragma unroll
    for (int j = 0; j < 4; ++j) {
        int c = cbase + ty + j * 8;
        tile[ty + j * 8][tx] =
            __builtin_nontemporal_load(&src[(size_t)c * PIX + (pbase + tx)]);
    }
    __syncthreads();
    #pragma unroll
    for (int j = 0; j < 4; ++j) {
        int p = pbase + ty + j * 8;
        dst[(size_t)p * CCH + (cbase + tx)] = tile[tx][ty + j * 8];
    }
}

// ---------------------------------------------------------------------------
// Kernel 2 (R7): wide-tile gather + invalid-skip.
// Ledger: NT hints -3%, occupancy null, pipelining -5%, write-span -2%.
// Surviving model: scattered-read path bound (~1.76 TB/s effective; 88%
// L2-miss on the 34.6 MB imgT set, ~1.4 misses/cy/XCD). The only lever that
// cuts miss count without scattering the writes: SKIP the 256B feature read
// for all-invalid queries (P = 0.7^6 = 11.8%), writing zeros to LDS instead.
// Valid path drops the *s multiply (s is identically 1.0 there).
// Structure per block (two c-half passes, h = 0,1):
//  A) threads 0..127 resolve cam/scale/base (NT loads).
//  B) 32 groups x 16 lanes: per VALID query read 256B (this c-half) as
//     16-lane f32x4 -> LDS feat[q][67]; invalid -> zeros. 2-way banks, free.
//  C) 8 waves x (csub 0..3): per c store two 256B NT f32x4 spans ->
//     512B contiguous per (c,block). 2-way banks, free.
// LDS: 128*67*4 + 128*8 = 35.4 KB -> 4 blocks/CU = 32 waves/CU.
// ---------------------------------------------------------------------------
__global__ __launch_bounds__(512, 8) void gather_wide_kernel(
    const float* __restrict__ imgT,     // (cam, y, x, c)
    const float* __restrict__ points,   // (cam, NQ, 2)
    const int*   __restrict__ valid,    // (cam, NQ) int32
    float*       __restrict__ out) {    // (c, NQ)
    __shared__ float feat[QT * FSTR];   // [q][67], c-half major
    __shared__ int   sbase[QT];
    __shared__ float sscale[QT];

    const int t     = threadIdx.x;
    const int qbase = blockIdx.x * QT;

    // ---- Phase A: resolve ----
    if (t < QT) {
        const int q = qbase + t;
        int sel = -1;
        #pragma unroll
        for (int cam = 0; cam < NCAM; ++cam)
            if (__builtin_nontemporal_load(&valid[(size_t)cam * NQ + q]) != 0)
                sel = cam;                                  // highest valid
        const int cam = (sel >= 0) ? sel : 0;
        sscale[t] = (sel >= 0) ? 1.0f : 0.0f;
        const f32x2 pt = __builtin_nontemporal_load(
            (const f32x2*)points + (size_t)cam * NQ + q);
        const int x = __float2int_rn(pt.x);   // RNE == jnp.round
        const int y = __float2int_rn(pt.y);
        sbase[t] = ((cam * IH + y) * IW + x) * CCH;   // word offset, < 2^31
    }
    __syncthreads();

    const int grp16  = t >> 4;     // 0..31
    const int lane16 = t & 15;
    const int l      = t & 63;
    const int wv     = t >> 6;     // wave 0..7
    const int qq     = l & 15;     // 0..15
    const int csub   = l >> 4;     // 0..3

    #pragma unroll
    for (int h = 0; h < 2; ++h) {
        // ---- Phase B: 256B coalesced reads (c-half h) -> LDS; skip invalid ----
        #pragma unroll
        for (int i = 0; i < 4; ++i) {
            const int ql = i * 32 + grp16;
            const int w  = ql * FSTR + 4 * lane16;
            if (sscale[ql] != 0.0f) {
                const f32x4 v =
                    *((const f32x4*)(imgT + sbase[ql] + h * CHALF) + lane16);
                feat[w + 0] = v.x;          // s == 1.0 on this path
                feat[w + 1] = v.y;
                feat[w + 2] = v.z;
                feat[w + 3] = v.w;
            } else {
                feat[w + 0] = 0.0f;         // no global read at all
                feat[w + 1] = 0.0f;
                feat[w + 2] = 0.0f;
                feat[w + 3] = 0.0f;
            }
        }
        __syncthreads();

        // ---- Phase C: LDS -> out, NT f32x4; 512B contiguous per (c,block) ----
        #pragma unroll
        for (int qh = 0; qh < 2; ++qh) {
            #pragma unroll
            for (int iter = 0; iter < 2; ++iter) {
                const int cl   = iter * 32 + wv * 4 + csub;   // 0..63
                const int c    = h * CHALF + cl;
                const int qoff = qh * 64 + 4 * qq;            // 0..124
                f32x4 v;
                v.x = feat[(qoff + 0) * FSTR + cl];
                v.y = feat[(qoff + 1) * FSTR + cl];
                v.z = feat[(qoff + 2) * FSTR + cl];
                v.w = feat[(qoff + 3) * FSTR + cl];
                __builtin_nontemporal_store(
                    v, (f32x4*)(out + (size_t)c * NQ + qbase + qoff));
            }
        }
        __syncthreads();   // next half overwrites feat
    }
}

// ---------------------------------------------------------------------------
// Fallback: direct gather from (cam, c, y, x) if workspace too small.
// ---------------------------------------------------------------------------
__global__ __launch_bounds__(256) void gather_direct_kernel(
    const float* __restrict__ img,
    const float* __restrict__ points,
    const int*   __restrict__ valid,
    float*       __restrict__ out) {
    const int q = blockIdx.x * 256 + threadIdx.x;

    int sel = -1;
    #pragma unroll
    for (int cam = 0; cam < NCAM; ++cam)
        if (valid[(size_t)cam * NQ + q] != 0) sel = cam;

    const float scale = (sel >= 0) ? 1.0f : 0.0f;
    const int cam = (sel >= 0) ? sel : 0;

    const float2 pt = ((const float2*)points)[(size_t)cam * NQ + q];
    const int x = __float2int_rn(pt.x);
    const int y = __float2int_rn(pt.y);

    const float* src = img + ((size_t)cam * CCH * IH + y) * IW + x;
    #pragma unroll 8
    for (int c = 0; c < CCH; ++c)
        out[(size_t)c * NQ + q] = src[(size_t)c * PIX] * scale;
}

extern "C" void kernel_launch(void* const* d_in, const int* in_sizes, int n_in,
                              void* d_out, int out_size, void* d_ws, size_t ws_size,
                              hipStream_t stream) {
    const float* img    = (const float*)d_in[0];
    const float* points = (const float*)d_in[1];
    const int*   valid  = (const int*)  d_in[2];
    float*       out    = (float*)d_out;

    const size_t need = (size_t)NCAM * CCH * IH * IW * sizeof(float);
    if (ws_size >= need) {
        float* imgT = (float*)d_ws;
        dim3 tb(32, 8, 1);
        dim3 tg(PIX / 32, CCH / 32, NCAM);
        transpose_kernel<<<tg, tb, 0, stream>>>(img, imgT);
        gather_wide_kernel<<<NQ / QT, 512, 0, stream>>>(imgT, points, valid, out);
    } else {
        gather_direct_kernel<<<NQ / 256, 256, 0, stream>>>(img, points, valid, out);
    }
}

// Round 10
// 402.093 us; speedup vs baseline: 1.0858x; 1.0032x over previous
//
#include <hip/hip_runtime.h>

#define NCAM 6
#define CCH  128
#define IH   64
#define IW   176
#define NQ   640000           // 200*200*16
#define PIX  (IH * IW)        // 11264
#define QT   128              // queries per block
#define CHALF 64              // channels per half-pass (LDS fits 128q x 64c)
#define FSTR  67              // feat stride: 64 c + 3 pad -> 2-way banks (free)

typedef float f32x2 __attribute__((ext_vector_type(2)));
typedef float f32x4 __attribute__((ext_vector_type(4)));

// ---------------------------------------------------------------------------
// Kernel 1: transpose img_feats (cam, c, y, x) -> (cam, y, x, c). ~15 us.
// ---------------------------------------------------------------------------
__global__ __launch_bounds__(256) void transpose_kernel(
    const float* __restrict__ in, float* __restrict__ out) {
    __shared__ float tile[32][33];
    const int cam   = blockIdx.z;
    const int pbase = blockIdx.x * 32;
    const int cbase = blockIdx.y * 32;
    const int tx = threadIdx.x, ty = threadIdx.y;

    const float* src = in  + (size_t)cam * CCH * PIX;
    float*       dst = out + (size_t)cam * PIX * CCH;

    #pragma unroll
    for (int j = 0; j < 4; ++j) {
        int c = cbase + ty + j * 8;
        tile[ty + j * 8][tx] =
            __builtin_nontemporal_load(&src[(size_t)c * PIX + (pbase + tx)]);
    }
    __syncthreads();
    #pragma unroll
    for (int j = 0; j < 4; ++j) {
        int p = pbase + ty + j * 8;
        dst[(size_t)p * CCH + (cbase + tx)] = tile[tx][ty + j * 8];
    }
}

// ---------------------------------------------------------------------------
// Kernel 2 (R10): wide-tile gather + CAM-ORDERED processing.
// Ledger: NT -3%, occupancy null, pipelining -5%, write-span -2%,
// invalid-skip -1%. None changed the L2 WORKING SET. Surviving model:
// L2-miss/fabric bound (12% hit on 34.6MB imgT vs 4MiB/XCD L2 under random
// access, ~289MB fabric traffic at ~1.8TB/s). The sel-cam distribution is
// skewed (P(5)=0.30 .. P(0)=0.05, cam5 slice 5.8MB gets ~17x reuse), so
// processing queries IN CAM ORDER shrinks the instantaneous chip-wide read
// working set to 1-2 cam slices (5.8-11.6MB) -> L2 hit up, fabric traffic
// down. Invalid queries sort last -> the 11.8% skip becomes wave-uniform.
// Phase A adds: LDS 7-bin count (atomicAdd) + prefix + scatter -> order[].
// Phase B walks order[] (LDS broadcast per 16-lane group). Phase C, tile
// geometry, write layout unchanged from R9.
// LDS: 128*67*4 + 128*12 + order/bins ~ 36.1 KB -> 4 blocks/CU.
// ---------------------------------------------------------------------------
__global__ __launch_bounds__(512, 8) void gather_wide_kernel(
    const float* __restrict__ imgT,     // (cam, y, x, c)
    const float* __restrict__ points,   // (cam, NQ, 2)
    const int*   __restrict__ valid,    // (cam, NQ) int32
    float*       __restrict__ out) {    // (c, NQ)
    __shared__ float feat[QT * FSTR];   // [q][67], c-half major
    __shared__ int   sbase[QT];
    __shared__ float sscale[QT];
    __shared__ int   order[QT];         // query ids, cam-sorted (invalid last)
    __shared__ int   bins[8];           // counts per bin (cam 0..5, invalid=6)
    __shared__ int   boff[8];           // exclusive offsets

    const int t     = threadIdx.x;
    const int qbase = blockIdx.x * QT;

    if (t < 8) bins[t] = 0;
    __syncthreads();

    // ---- Phase A: resolve + cam-binning ----
    int myb = 0, myr = 0;
    if (t < QT) {
        const int q = qbase + t;
        int sel = -1;
        #pragma unroll
        for (int cam = 0; cam < NCAM; ++cam)
            if (__builtin_nontemporal_load(&valid[(size_t)cam * NQ + q]) != 0)
                sel = cam;                                  // highest valid
        const int cam = (sel >= 0) ? sel : 0;
        sscale[t] = (sel >= 0) ? 1.0f : 0.0f;
        const f32x2 pt = __builtin_nontemporal_load(
            (const f32x2*)points + (size_t)cam * NQ + q);
        const int x = __float2int_rn(pt.x);   // RNE == jnp.round
        const int y = __float2int_rn(pt.y);
        sbase[t] = ((cam * IH + y) * IW + x) * CCH;   // word offset, < 2^31
        myb = (sel >= 0) ? sel : 6;
        myr = atomicAdd(&bins[myb], 1);               // rank within bin
    }
    __syncthreads();
    if (t == 0) {                                     // 7-bin exclusive scan
        int acc = 0;
        #pragma unroll
        for (int k = 0; k < 7; ++k) { boff[k] = acc; acc += bins[k]; }
    }
    __syncthreads();
    if (t < QT) order[boff[myb] + myr] = t;
    __syncthreads();

    const int grp16  = t >> 4;     // 0..31
    const int lane16 = t & 15;
    const int l      = t & 63;
    const int wv     = t >> 6;     // wave 0..7
    const int qq     = l & 15;     // 0..15
    const int csub   = l >> 4;     // 0..3

    #pragma unroll
    for (int h = 0; h < 2; ++h) {
        // ---- Phase B: cam-ordered 256B reads -> LDS; invalid (tail) -> zeros ----
        #pragma unroll
        for (int i = 0; i < 4; ++i) {
            const int ql = order[i * 32 + grp16];     // broadcast per group
            const int w  = ql * FSTR + 4 * lane16;
            if (sscale[ql] != 0.0f) {
                const f32x4 v =
                    *((const f32x4*)(imgT + sbase[ql] + h * CHALF) + lane16);
                feat[w + 0] = v.x;          // s == 1.0 on this path
                feat[w + 1] = v.y;
                feat[w + 2] = v.z;
                feat[w + 3] = v.w;
            } else {
                feat[w + 0] = 0.0f;         // no global read at all
                feat[w + 1] = 0.0f;
                feat[w + 2] = 0.0f;
                feat[w + 3] = 0.0f;
            }
        }
        __syncthreads();

        // ---- Phase C: LDS -> out, NT f32x4; 512B contiguous per (c,block) ----
        #pragma unroll
        for (int qh = 0; qh < 2; ++qh) {
            #pragma unroll
            for (int iter = 0; iter < 2; ++iter) {
                const int cl   = iter * 32 + wv * 4 + csub;   // 0..63
                const int c    = h * CHALF + cl;
                const int qoff = qh * 64 + 4 * qq;            // 0..124
                f32x4 v;
                v.x = feat[(qoff + 0) * FSTR + cl];
                v.y = feat[(qoff + 1) * FSTR + cl];
                v.z = feat[(qoff + 2) * FSTR + cl];
                v.w = feat[(qoff + 3) * FSTR + cl];
                __builtin_nontemporal_store(
                    v, (f32x4*)(out + (size_t)c * NQ + qbase + qoff));
            }
        }
        __syncthreads();   // next half overwrites feat
    }
}

// ---------------------------------------------------------------------------
// Fallback: direct gather from (cam, c, y, x) if workspace too small.
// ---------------------------------------------------------------------------
__global__ __launch_bounds__(256) void gather_direct_kernel(
    const float* __restrict__ img,
    const float* __restrict__ points,
    const int*   __restrict__ valid,
    float*       __restrict__ out) {
    const int q = blockIdx.x * 256 + threadIdx.x;

    int sel = -1;
    #pragma unroll
    for (int cam = 0; cam < NCAM; ++cam)
        if (valid[(size_t)cam * NQ + q] != 0) sel = cam;

    const float scale = (sel >= 0) ? 1.0f : 0.0f;
    const int cam = (sel >= 0) ? sel : 0;

    const float2 pt = ((const float2*)points)[(size_t)cam * NQ + q];
    const int x = __float2int_rn(pt.x);
    const int y = __float2int_rn(pt.y);

    const float* src = img + ((size_t)cam * CCH * IH + y) * IW + x;
    #pragma unroll 8
    for (int c = 0; c < CCH; ++c)
        out[(size_t)c * NQ + q] = src[(size_t)c * PIX] * scale;
}

extern "C" void kernel_launch(void* const* d_in, const int* in_sizes, int n_in,
                              void* d_out, int out_size, void* d_ws, size_t ws_size,
                              hipStream_t stream) {
    const float* img    = (const float*)d_in[0];
    const float* points = (const float*)d_in[1];
    const int*   valid  = (const int*)  d_in[2];
    float*       out    = (float*)d_out;

    const size_t need = (size_t)NCAM * CCH * IH * IW * sizeof(float);
    if (ws_size >= need) {
        float* imgT = (float*)d_ws;
        dim3 tb(32, 8, 1);
        dim3 tg(PIX / 32, CCH / 32, NCAM);
        transpose_kernel<<<tg, tb, 0, stream>>>(img, imgT);
        gather_wide_kernel<<<NQ / QT, 512, 0, stream>>>(imgT, points, valid, out);
    } else {
        gather_direct_kernel<<<NQ / 256, 256, 0, stream>>>(img, points, valid, out);
    }
}